// Round 8
// baseline (229.587 us; speedup 1.0000x reference)
//
#include <hip/hip_runtime.h>
#include <hip/hip_bf16.h>
#include <math.h>

#define N_IN 85680
#define PRE_K 5000
#define POST_K 750
#define NW 79            // ceil(PRE_K/64) words
#define NPAD 5056        // NW*64
#define STR 80           // mask row stride in u64 (79 used, 1 pad)
#define HSIZE 8192       // linear buckets over score-bit range (0.02, +inf)
#define CAND_MAX 8192
#define CONF_THR 0.02f
#define NMS_THR 0.4f
#define BITS_THR 0x3CA3D70Bu  // bits of smallest float > 0.02f
#define KMAX 64          // row-DMA slots per word (= max kept/word -> NO overflow path)

typedef unsigned int u32;
typedef unsigned long long u64;

// opacity barrier: prevents FMA contraction so f32 math bit-matches numpy ref
__device__ __forceinline__ float opaquef(float x) { asm volatile("" : "+v"(x)); return x; }

// wave-uniform 64-bit broadcast via v_readlane (src lane must be uniform)
__device__ __forceinline__ u64 readlane64(u64 v, int l) {
    u32 lo = __builtin_amdgcn_readlane((u32)v, l);
    u32 hi = __builtin_amdgcn_readlane((u32)(v >> 32), l);
    return ((u64)hi << 32) | (u64)lo;
}

// monotone bucket of a score's float bits (score > CONF_THR guaranteed)
__device__ __forceinline__ u32 bucket_of(u32 bits) {
    u32 b = (bits - BITS_THR) >> 13;
    return b >= HSIZE ? (HSIZE - 1) : b;
}

// async global->LDS 16B: global src is PER-LANE, LDS dest is wave-uniform base
// (HW writes base + lane*16)
__device__ __forceinline__ void gload_lds16(const void* g, void* l) {
    __builtin_amdgcn_global_load_lds(
        (const __attribute__((address_space(1))) void*)g,
        (__attribute__((address_space(3))) void*)l, 16, 0, 0);
}

// ---------------- fused histogram + suffix-scan (1 block); also zeroes bfill/validm ----------------
__global__ __launch_bounds__(1024) void histscan_kernel(const float2* __restrict__ conf2,
                                                        u32* __restrict__ bsel,
                                                        u32* __restrict__ bstart,
                                                        u32* __restrict__ bfill,
                                                        u64* __restrict__ validm) {
    __shared__ u32 h[HSIZE];
    __shared__ u32 tot[1024];
    int c = threadIdx.x;
    for (int b = c; b < HSIZE; b += 1024) h[b] = 0u;
    __syncthreads();
    for (int i = c; i < N_IN; i += 1024) {
        float s = conf2[i].y;
        if (s > CONF_THR) atomicAdd(&h[bucket_of(__float_as_uint(s))], 1u);
    }
    __syncthreads();
    u32 lh[8];
    u32 t = 0;
#pragma unroll
    for (int k = 0; k < 8; ++k) { lh[k] = h[c * 8 + k]; t += lh[k]; }
    tot[c] = t;
    __syncthreads();
    for (int d = 1; d < 1024; d <<= 1) {
        u32 v = tot[c] + ((c + d < 1024) ? tot[c + d] : 0u);
        __syncthreads();
        tot[c] = v;
        __syncthreads();
    }
    u32 above = (c + 1 < 1024) ? tot[c + 1] : 0u;  // suffix starting at next chunk
    u32 s = above;
    for (int k = 7; k >= 0; --k) { bstart[c * 8 + k] = s; s += lh[k]; }
    // bsel = max bucket with inclusive-suffix >= PRE_K (boundary thread unique)
    if (above < PRE_K && above + t >= PRE_K) {
        u32 cum = above;
        for (int k = 7; k >= 0; --k) {
            cum += lh[k];
            if (cum >= PRE_K) { bsel[0] = (u32)(c * 8 + k); break; }
        }
    }
    if (c == 0 && tot[0] < PRE_K) bsel[0] = 0u;   // fewer than PRE_K valid: take all
    // zero the buffers later kernels accumulate into (replaces hipMemsetAsync)
    for (int b = c; b < HSIZE; b += 1024) bfill[b] = 0u;
    if (c < 128) validm[c] = 0ull;
}

// ---------------- scatter candidates bucket-grouped ----------------
__global__ __launch_bounds__(256) void compact_kernel(const float2* __restrict__ conf2,
                                                      const u32* __restrict__ bsel,
                                                      const u32* __restrict__ bstart,
                                                      u32* __restrict__ bfill,
                                                      u64* __restrict__ cand) {
    int i = blockIdx.x * 256 + threadIdx.x;
    if (i >= N_IN) return;
    float sc = conf2[i].y;
    if (!(sc > CONF_THR)) return;
    u32 bits = __float_as_uint(sc);
    u32 b = bucket_of(bits);
    if (b < bsel[0]) return;
    u32 pos = bstart[b] + atomicAdd(&bfill[b], 1u);
    // key: high = score bits, low = ~i  (greater key == higher score, then lower index)
    if (pos < CAND_MAX) cand[pos] = ((u64)bits << 32) | (u64)(u32)(~(u32)i);
}

// ---------------- fused: exact rank within bucket + decode -> rows/boxes/validm ----------------
__global__ __launch_bounds__(256) void rankdec_kernel(const u64* __restrict__ cand,
                                                      const u32* __restrict__ bstart,
                                                      const u32* __restrict__ bfill,
                                                      const u32* __restrict__ bsel,
                                                      const float4* __restrict__ loc4,
                                                      const float4* __restrict__ pri4,
                                                      const float* __restrict__ lmk,
                                                      const int* __restrict__ imw,
                                                      const int* __restrict__ imh,
                                                      float4* __restrict__ rows4,
                                                      float4* __restrict__ boxes,
                                                      u64* __restrict__ validm) {
    u32 bs = bsel[0];
    u32 total = bstart[bs] + bfill[bs];
    if (total > CAND_MAX) total = CAND_MAX;
    float W = (float)(*imw), H = (float)(*imh);
    for (u32 s = blockIdx.x * blockDim.x + threadIdx.x; s < total;
         s += gridDim.x * blockDim.x) {
        u64 key = cand[s];
        u32 b = bucket_of((u32)(key >> 32));
        u32 st = bstart[b];
        u32 en = st + bfill[b];
        if (en > CAND_MAX) en = CAND_MAX;
        u32 r = st;
        for (u32 j = st; j < en; ++j) r += (cand[j] > key) ? 1u : 0u;
        if (r >= PRE_K) continue;
        u32 i = ~(u32)key;
        float score = __uint_as_float((u32)(key >> 32));
        float4 L = loc4[i];
        float4 P = pri4[i];
        float cx = P.x + opaquef((L.x * 0.1f) * P.z);
        float cy = P.y + opaquef((L.y * 0.1f) * P.w);
        // exp in f64 then round: ~correctly-rounded f32 exp (closest to numpy)
        float bw = P.z * (float)exp((double)(L.z * 0.2f));
        float bh = P.w * (float)exp((double)(L.w * 0.2f));
        float hw = opaquef(bw * 0.5f), hh = opaquef(bh * 0.5f);
        float x0 = (cx - hw) * W, y0 = (cy - hh) * H;
        float x1 = (cx + hw) * W, y1 = (cy + hh) * H;
        boxes[r] = make_float4(x0, y0, x1, y1);
        float lm[10];
#pragma unroll
        for (int p = 0; p < 5; ++p) {
            float2 q = ((const float2*)lmk)[(size_t)i * 5 + p];
            lm[2 * p]     = (P.x + opaquef((q.x * 0.1f) * P.z)) * W;
            lm[2 * p + 1] = (P.y + opaquef((q.y * 0.1f) * P.w)) * H;
        }
        float4* row = rows4 + (size_t)r * 4;
        row[0] = make_float4(x0, y0, x1, y1);
        row[1] = make_float4(score, lm[0], lm[1], lm[2]);
        row[2] = make_float4(lm[3], lm[4], lm[5], lm[6]);
        row[3] = make_float4(lm[7], lm[8], lm[9], 0.f);
        atomicOr(&validm[r >> 6], 1ull << (r & 63));
    }
}

// ---------------- pairwise IoU suppression bitmask (flat triangular grid) ----------------
__global__ __launch_bounds__(64) void mask_kernel(const float4* __restrict__ boxes,
                                                  u64* __restrict__ mask) {
    // flat bid -> (rc, cc) with cc >= rc; row rc owns NW-rc blocks
    int rem = blockIdx.x, rc = 0;
    while (rem >= NW - rc) { rem -= NW - rc; ++rc; }
    int cc = rc + rem;
    __shared__ float4 cb[64];
    int t = threadIdx.x;
    cb[t] = boxes[cc * 64 + t];
    int i = rc * 64 + t;
    float4 bi = boxes[i];
    __syncthreads();
    float areai = (bi.z - bi.x) * (bi.w - bi.y);
    u64 word = 0ull;
    int jbase = cc * 64;
#pragma unroll 4
    for (int k = 0; k < 64; ++k) {
        float4 bj = cb[k];
        float areaj = (bj.z - bj.x) * (bj.w - bj.y);
        float ltx = fmaxf(bi.x, bj.x), lty = fmaxf(bi.y, bj.y);
        float rbx = fminf(bi.z, bj.z), rby = fminf(bi.w, bj.w);
        float wx = fmaxf(rbx - ltx, 0.f), wy = fmaxf(rby - lty, 0.f);
        float inter = opaquef(wx * wy);
        float uni = fmaxf(areai + areaj - inter, 1e-12f);
        float iou = inter / uni;
        if ((jbase + k) > i && iou > NMS_THR) word |= (1ull << k);
    }
    if (i < PRE_K) mask[(size_t)i * STR + cc] = word;  // rows >= PRE_K not allocated
}

// ---------------- single-wave greedy NMS reduce (v8: KMAX=64, zero overflow) ----------------
// Counted-vmcnt invariant: per word issue exactly [2 diag reg-loads, then 64
// row-DMAs (dummy-padded)].  vmcnt(63) at word start then PROVABLY drains
// everything with >=64 younger ops: diag(w) (64 younger) and all rows(w-2)
// (>=66 younger) — while rows(w-1)[1..63] stay in flight.  No per-kept-box
// latency anywhere: col-(w+1) register bits (acc) bridge adjacent words, and
// full rows fold from LDS with a 2-word lag.
__global__ __launch_bounds__(64) void reduce_kernel(const u64* __restrict__ mask,
                                                    const u64* __restrict__ validm,
                                                    u64* __restrict__ keepw) {
    int lane = threadIdx.x;
    __shared__ __align__(16) u64 prop[2][KMAX * 128];  // 2 parity slabs x 64 slots x 1KB = 128 KiB

    u64 remv0 = 0ull, remv1 = 0ull, keep0 = 0ull, keep1 = 0ull;
    u64 valid0 = validm[lane];
    bool lo2 = (lane < NW - 64);
    u64 valid1 = lo2 ? validm[64 + lane] : 0ull;
    u32 total = 0;
    u64 acc = 0ull;           // col-w suppression from word w-1's kept boxes
    int kprev = 0, kprev2 = 0;

    // prologue: diag loads for word 0 (rows lane, cols 0 and 1)
    u64 dl_a = mask[(size_t)lane * STR + 0];
    u64 dl_b = mask[(size_t)lane * STR + 1];

    for (int w = 0; w < NW; ++w) {
        if (w == 0) { asm volatile("s_waitcnt vmcnt(0)" ::: "memory"); }
        else        { asm volatile("s_waitcnt vmcnt(63)" ::: "memory"); }
        __builtin_amdgcn_sched_barrier(0);
        u64 d_cur = dl_a, d_nxt = dl_b;   // cols w, w+1 of word-w rows (drained above)

        // issue diag reg-loads for word w+1 FIRST (before any row DMA: accounting)
        if (w + 1 < NW) {
            int r = (w + 1) * 64 + lane;
            if (r > PRE_K - 1) r = PRE_K - 1;      // rows >= 5000: clamp (bits unused)
            const u64* p = mask + (size_t)r * STR;
            dl_a = p[w + 1];
            dl_b = p[w + 2];                        // w+2 <= 79 < STR always in-bounds
        }
        __builtin_amdgcn_sched_barrier(0);

        // fold word w-2's kept rows from LDS (their DMAs drained by the wait above)
        u64* pslab = prop[w & 1];
        for (int j = 0; j < kprev2; ++j) {
            remv0 |= pslab[j * 128 + lane];
            if (lo2) remv1 |= pslab[j * 128 + 64 + lane];
        }
        __builtin_amdgcn_sched_barrier(0);

        // decide word w
        u64 remw, valw;
        if (w < 64) { remw = readlane64(remv0, w); valw = readlane64(valid0, w); }
        else        { remw = readlane64(remv1, w - 64); valw = readlane64(valid1, w - 64); }
        remw |= acc;
        u64 cur = valw & ~remw;            // wave-uniform
        u64 keptw = 0ull, accn = 0ull;
        int kreal = 0;
        const char* wbase = (const char*)(mask + ((size_t)w << 6) * STR);
        while (cur) {
            int b = __ffsll(cur) - 1;
            keptw |= (1ull << b);
            // row DMA for the 2-word-lag fold (kreal < 64 always: kept <= 64/word)
            gload_lds16(wbase + (size_t)b * (STR * 8) + lane * 16, &pslab[kreal * 128]);
            ++kreal;
            accn |= readlane64(d_nxt, b);  // suppress word w+1 via in-reg col w+1
            u64 roww = readlane64(d_cur, b);
            cur &= ~(roww | (1ull << b));
        }

        if (w < 64) { if (lane == w) keep0 |= keptw; }
        else if (lane == w - 64) keep1 |= keptw;
        total += (u32)__popcll(keptw);
        if (total >= POST_K) break;        // output fully determined (skip dummies)

        for (int kk = kreal; kk < KMAX; ++kk)   // dummy-pad to static 64 issues/word
            gload_lds16(wbase + lane * 16, &pslab[kk * 128]);

        acc = accn;
        kprev2 = kprev;
        kprev = kreal;
    }

    // drain in-flight DMAs before workgroup teardown (LDS dealloc safety)
    asm volatile("s_waitcnt vmcnt(0)" ::: "memory");
    keepw[lane] = keep0;
    keepw[64 + lane] = keep1;
}

// ---------------- scatter kept rows (rank < POST_K) + zero-fill tail ----------------
__global__ __launch_bounds__(256) void scatter_kernel(const float* __restrict__ rows,
                                                      const u64* __restrict__ keepw,
                                                      float* __restrict__ out) {
    int r = blockIdx.x * 256 + threadIdx.x;
    if (r >= PRE_K) return;
    int w = r >> 6, b = r & 63;
    u64 kw = keepw[w];
    bool kept = (kw >> b) & 1ull;
    if (kept) {
        u32 rank = (u32)__popcll(kw & ((1ull << b) - 1ull));
        for (int u = 0; u < w; ++u) rank += (u32)__popcll(keepw[u]);  // L1-cached 640B
        if (rank < POST_K) {
            const float* src = rows + (size_t)r * 16;
            float* dst = out + (size_t)rank * 15;
#pragma unroll
            for (int c = 0; c < 15; ++c) dst[c] = src[c];
        }
    }
    if (r < POST_K) {  // zero-fill ranks never produced (out is not pre-zeroed)
        u32 totk = 0;
        for (int u = 0; u < NW; ++u) totk += (u32)__popcll(keepw[u]);
        if ((u32)r >= totk) {
            float* dst = out + (size_t)r * 15;
#pragma unroll
            for (int c = 0; c < 15; ++c) dst[c] = 0.f;
        }
    }
}

extern "C" void kernel_launch(void* const* d_in, const int* in_sizes, int n_in,
                              void* d_out, int out_size, void* d_ws, size_t ws_size,
                              hipStream_t stream) {
    const float* loc = (const float*)d_in[0];
    const float2* conf2 = (const float2*)d_in[1];
    const float* lmk = (const float*)d_in[2];
    const float* pri = (const float*)d_in[3];
    const int* imw = (const int*)d_in[4];
    const int* imh = (const int*)d_in[5];
    float* out = (float*)d_out;
    char* base = (char*)d_ws;

    // workspace layout (bytes); total 3,767,232 (< 3,808,896 proven in R3-R7)
    u32* bfill  = (u32*)(base + 32768);     //  32768  (zeroed by histscan)
    u32* bsel   = (u32*)(base + 65536);     //  64     (always written by histscan)
    u64* validm = (u64*)(base + 65600);     //  1024   (zeroed by histscan)
    u64* keepw  = (u64*)(base + 66624);     //  1024   (fully written by reduce)
    u32* bstart = (u32*)(base + 67648);     //  32768
    u64* cand   = (u64*)(base + 100416);    //  65536
    float* rows = (float*)(base + 165952);  //  320000 (5000 x 16)
    float4* boxes = (float4*)(base + 485952); // 80896 (NPAD x 16; pads read-garbage-OK)
    u64* mask   = (u64*)(base + 566848);    //  3200384 (PRE_K x STR x 8 + diag overrun)

    histscan_kernel<<<1, 1024, 0, stream>>>(conf2, bsel, bstart, bfill, validm);
    compact_kernel<<<(N_IN + 255) / 256, 256, 0, stream>>>(conf2, bsel, bstart, bfill, cand);
    rankdec_kernel<<<24, 256, 0, stream>>>(cand, bstart, bfill, bsel, (const float4*)loc,
                                           (const float4*)pri, lmk, imw, imh,
                                           (float4*)rows, boxes, validm);
    mask_kernel<<<NW * (NW + 1) / 2, 64, 0, stream>>>(boxes, mask);
    reduce_kernel<<<1, 64, 0, stream>>>(mask, validm, keepw);
    scatter_kernel<<<(PRE_K + 255) / 256, 256, 0, stream>>>(rows, keepw, out);
}

// Round 9
// 141.695 us; speedup vs baseline: 1.6203x; 1.6203x over previous
//
#include <hip/hip_runtime.h>
#include <hip/hip_bf16.h>
#include <math.h>

#define N_IN 85680
#define PRE_K 5000
#define POST_K 750
#define NW 79            // ceil(PRE_K/64) words
#define NPAD 5056        // NW*64
#define STR 80           // mask row stride in u64 (79 used, 1 pad)
#define HSIZE 8192       // linear buckets over score-bit range (0.02, +inf)
#define CAND_MAX 8192
#define CONF_THR 0.02f
#define NMS_THR 0.4f
#define BITS_THR 0x3CA3D70Bu  // bits of smallest float > 0.02f
#define SBN 5            // super-blocks of 1024 boxes (5*1024 covers NPAD)

typedef unsigned int u32;
typedef unsigned long long u64;

// opacity barrier: prevents FMA contraction so f32 math bit-matches numpy ref
__device__ __forceinline__ float opaquef(float x) { asm volatile("" : "+v"(x)); return x; }

// monotone bucket of a score's float bits (score > CONF_THR guaranteed)
__device__ __forceinline__ u32 bucket_of(u32 bits) {
    u32 b = (bits - BITS_THR) >> 13;
    return b >= HSIZE ? (HSIZE - 1) : b;
}

// ---------------- fused histogram + suffix-scan (1 block); also zeroes bfill/validm ----------------
__global__ __launch_bounds__(1024) void histscan_kernel(const float2* __restrict__ conf2,
                                                        u32* __restrict__ bsel,
                                                        u32* __restrict__ bstart,
                                                        u32* __restrict__ bfill,
                                                        u64* __restrict__ validm) {
    __shared__ u32 h[HSIZE];
    __shared__ u32 tot[1024];
    int c = threadIdx.x;
    for (int b = c; b < HSIZE; b += 1024) h[b] = 0u;
    __syncthreads();
    for (int i = c; i < N_IN; i += 1024) {
        float s = conf2[i].y;
        if (s > CONF_THR) atomicAdd(&h[bucket_of(__float_as_uint(s))], 1u);
    }
    __syncthreads();
    u32 lh[8];
    u32 t = 0;
#pragma unroll
    for (int k = 0; k < 8; ++k) { lh[k] = h[c * 8 + k]; t += lh[k]; }
    tot[c] = t;
    __syncthreads();
    for (int d = 1; d < 1024; d <<= 1) {
        u32 v = tot[c] + ((c + d < 1024) ? tot[c + d] : 0u);
        __syncthreads();
        tot[c] = v;
        __syncthreads();
    }
    u32 above = (c + 1 < 1024) ? tot[c + 1] : 0u;  // suffix starting at next chunk
    u32 s = above;
    for (int k = 7; k >= 0; --k) { bstart[c * 8 + k] = s; s += lh[k]; }
    // bsel = max bucket with inclusive-suffix >= PRE_K (boundary thread unique)
    if (above < PRE_K && above + t >= PRE_K) {
        u32 cum = above;
        for (int k = 7; k >= 0; --k) {
            cum += lh[k];
            if (cum >= PRE_K) { bsel[0] = (u32)(c * 8 + k); break; }
        }
    }
    if (c == 0 && tot[0] < PRE_K) bsel[0] = 0u;   // fewer than PRE_K valid: take all
    // zero the buffers later kernels accumulate into (replaces hipMemsetAsync)
    for (int b = c; b < HSIZE; b += 1024) bfill[b] = 0u;
    if (c < 128) validm[c] = 0ull;
}

// ---------------- scatter candidates bucket-grouped ----------------
__global__ __launch_bounds__(256) void compact_kernel(const float2* __restrict__ conf2,
                                                      const u32* __restrict__ bsel,
                                                      const u32* __restrict__ bstart,
                                                      u32* __restrict__ bfill,
                                                      u64* __restrict__ cand) {
    int i = blockIdx.x * 256 + threadIdx.x;
    if (i >= N_IN) return;
    float sc = conf2[i].y;
    if (!(sc > CONF_THR)) return;
    u32 bits = __float_as_uint(sc);
    u32 b = bucket_of(bits);
    if (b < bsel[0]) return;
    u32 pos = bstart[b] + atomicAdd(&bfill[b], 1u);
    // key: high = score bits, low = ~i  (greater key == higher score, then lower index)
    if (pos < CAND_MAX) cand[pos] = ((u64)bits << 32) | (u64)(u32)(~(u32)i);
}

// ---------------- fused: exact rank within bucket + decode -> rows/boxes/validm ----------------
__global__ __launch_bounds__(256) void rankdec_kernel(const u64* __restrict__ cand,
                                                      const u32* __restrict__ bstart,
                                                      const u32* __restrict__ bfill,
                                                      const u32* __restrict__ bsel,
                                                      const float4* __restrict__ loc4,
                                                      const float4* __restrict__ pri4,
                                                      const float* __restrict__ lmk,
                                                      const int* __restrict__ imw,
                                                      const int* __restrict__ imh,
                                                      float4* __restrict__ rows4,
                                                      float4* __restrict__ boxes,
                                                      u64* __restrict__ validm) {
    u32 bs = bsel[0];
    u32 total = bstart[bs] + bfill[bs];
    if (total > CAND_MAX) total = CAND_MAX;
    float W = (float)(*imw), H = (float)(*imh);
    for (u32 s = blockIdx.x * blockDim.x + threadIdx.x; s < total;
         s += gridDim.x * blockDim.x) {
        u64 key = cand[s];
        u32 b = bucket_of((u32)(key >> 32));
        u32 st = bstart[b];
        u32 en = st + bfill[b];
        if (en > CAND_MAX) en = CAND_MAX;
        u32 r = st;
        for (u32 j = st; j < en; ++j) r += (cand[j] > key) ? 1u : 0u;
        if (r >= PRE_K) continue;
        u32 i = ~(u32)key;
        float score = __uint_as_float((u32)(key >> 32));
        float4 L = loc4[i];
        float4 P = pri4[i];
        float cx = P.x + opaquef((L.x * 0.1f) * P.z);
        float cy = P.y + opaquef((L.y * 0.1f) * P.w);
        // exp in f64 then round: ~correctly-rounded f32 exp (closest to numpy)
        float bw = P.z * (float)exp((double)(L.z * 0.2f));
        float bh = P.w * (float)exp((double)(L.w * 0.2f));
        float hw = opaquef(bw * 0.5f), hh = opaquef(bh * 0.5f);
        float x0 = (cx - hw) * W, y0 = (cy - hh) * H;
        float x1 = (cx + hw) * W, y1 = (cy + hh) * H;
        boxes[r] = make_float4(x0, y0, x1, y1);
        float lm[10];
#pragma unroll
        for (int p = 0; p < 5; ++p) {
            float2 q = ((const float2*)lmk)[(size_t)i * 5 + p];
            lm[2 * p]     = (P.x + opaquef((q.x * 0.1f) * P.z)) * W;
            lm[2 * p + 1] = (P.y + opaquef((q.y * 0.1f) * P.w)) * H;
        }
        float4* row = rows4 + (size_t)r * 4;
        row[0] = make_float4(x0, y0, x1, y1);
        row[1] = make_float4(score, lm[0], lm[1], lm[2]);
        row[2] = make_float4(lm[3], lm[4], lm[5], lm[6]);
        row[3] = make_float4(lm[7], lm[8], lm[9], 0.f);
        atomicOr(&validm[r >> 6], 1ull << (r & 63));
    }
}

// ---------------- symmetric IoU bitmask, LOWER-triangle words only ----------------
// Row i, word cc (cc <= i>>6): bit k = (iou(i, cc*64+k) > thr), self/upper bits
// included in the diagonal word — the fixpoint masks to strictly-below-i.
__global__ __launch_bounds__(64) void mask_kernel(const float4* __restrict__ boxes,
                                                  u64* __restrict__ mask) {
    // flat bid -> (rc, cc) with cc <= rc; row rc owns rc+1 blocks
    int rem = blockIdx.x, rc = 0;
    while (rem >= rc + 1) { rem -= rc + 1; ++rc; }
    int cc = rem;
    __shared__ float4 cb[64];
    int t = threadIdx.x;
    cb[t] = boxes[cc * 64 + t];
    int i = rc * 64 + t;
    float4 bi = boxes[i];
    __syncthreads();
    float areai = (bi.z - bi.x) * (bi.w - bi.y);
    u64 word = 0ull;
#pragma unroll 4
    for (int k = 0; k < 64; ++k) {
        float4 bj = cb[k];
        float areaj = (bj.z - bj.x) * (bj.w - bj.y);
        float ltx = fmaxf(bi.x, bj.x), lty = fmaxf(bi.y, bj.y);
        float rbx = fminf(bi.z, bj.z), rby = fminf(bi.w, bj.w);
        float wx = fmaxf(rbx - ltx, 0.f), wy = fmaxf(rby - lty, 0.f);
        float inter = opaquef(wx * wy);
        float uni = fmaxf(areai + areaj - inter, 1e-12f);
        float iou = inter / uni;
        if (iou > NMS_THR) word |= (1ull << k);
    }
    if (i < PRE_K) mask[(size_t)i * STR + cc] = word;  // rows >= PRE_K not allocated
}

// ---------------- Jacobi-fixpoint greedy NMS + fused scatter (1 block, 1024 thr) ---------
// keep_i = valid_i & ~OR_{j<i}(keep_j & iou_ij>thr) — greedy NMS is the unique
// fixpoint; Jacobi iteration converges in <= max suppression-chain depth rounds
// (boxes become final in index order as their predecessors finalize).
// Thread tid owns box sb*1024+tid; its masked row lives in 16 u64 REGISTERS;
// the keep vector is 16 u64 in LDS (broadcast reads). One round = 16 AND-ORs +
// __ballot + 2 barriers. Super-blocks beyond the first run only if kept < 750.
__global__ __launch_bounds__(1024) void reduce_scatter_kernel(const u64* __restrict__ mask,
                                                              const u64* __restrict__ validm,
                                                              const float* __restrict__ rows,
                                                              float* __restrict__ out) {
    int tid = threadIdx.x;
    int wave = tid >> 6, lane = tid & 63;
    __shared__ u64 keepAll[96];   // final keep words (79 used), zero-init
    __shared__ u64 keepL[16];     // current super-block keep words
    __shared__ u32 flags[2];
    __shared__ u32 wpref[96];
    __shared__ u32 totsh;
    for (int k = tid; k < 96; k += 1024) keepAll[k] = 0ull;
    if (tid < 2) flags[tid] = 0u;
    if (tid == 0) totsh = 0u;
    __syncthreads();

    for (int sb = 0; sb < SBN; ++sb) {
        int i = sb * 1024 + tid;        // my box
        int iw = i >> 6;                // my global word
        int wbase = sb * 16;
        int nwloc = NW - wbase; if (nwloc > 16) nwloc = 16;
        bool wactive = (wave < nwloc);
        bool rowok = (i < PRE_K);
        int ic = rowok ? i : (PRE_K - 1);   // clamp: invalid rows never matter
        const u64* rp = mask + (size_t)ic * STR;
        // frozen suppression from already-finalized super-blocks
        u64 fr = 0ull;
        for (int w2 = 0; w2 < wbase; ++w2) fr |= keepAll[w2] & rp[w2];
        // my row (registers), masked to strictly-below-me
        u64 row[16];
#pragma unroll
        for (int k = 0; k < 16; ++k) {
            u64 v = 0ull;
            if (k < wave)       v = rp[wbase + k];
            else if (k == wave) v = rp[wbase + k] & ((1ull << lane) - 1ull);
            row[k] = v;
        }
        bool okv = rowok && ((validm[iw] >> lane) & 1ull) && (fr == 0ull);
        // init: optimistic all-valid kept
        u64 bw0 = __ballot(okv);
        if (lane == 0 && wave < 16) keepL[wave] = wactive ? bw0 : 0ull;
        __syncthreads();
        int p = 0;
        for (int it = 0; it < 1200; ++it) {
            u64 sup = 0ull;
#pragma unroll
            for (int k = 0; k < 16; ++k) sup |= keepL[k] & row[k];
            bool nb = okv && (sup == 0ull);
            u64 nword = __ballot(nb);
            bool ch = (lane == 0) && wactive && (nword != keepL[wave]);
            __syncthreads();                 // everyone done reading old keepL
            if (lane == 0 && wactive) keepL[wave] = nword;
            if (ch) atomicOr(&flags[p], 1u);
            if (tid == 0) flags[p ^ 1] = 0u; // pre-clear next parity
            __syncthreads();
            if (flags[p] == 0u) break;       // converged (uniform)
            p ^= 1;
        }
        // commit this super-block
        if (lane == 0 && wactive) keepAll[wbase + wave] = keepL[wave];
        __syncthreads();
        if (tid == 0) {
            u32 s = 0;
            for (int k = 0; k < nwloc; ++k) s += (u32)__popcll(keepL[k]);
            totsh += s;
        }
        __syncthreads();
        if (totsh >= POST_K || wbase + nwloc >= NW) break;  // later keeps: rank >= 750
    }

    // word-prefix ranks
    if (tid == 0) {
        u32 s = 0;
        for (int w = 0; w < NW; ++w) { wpref[w] = s; s += (u32)__popcll(keepAll[w]); }
        wpref[NW] = s;
    }
    __syncthreads();
    u32 totk = wpref[NW]; if (totk > POST_K) totk = POST_K;
    // scatter kept rows with rank < POST_K
    for (int r = tid; r < PRE_K; r += 1024) {
        int w = r >> 6, b = r & 63;
        u64 kw = keepAll[w];
        if ((kw >> b) & 1ull) {
            u32 rank = wpref[w] + (u32)__popcll(kw & ((1ull << b) - 1ull));
            if (rank < POST_K) {
                const float* src = rows + (size_t)r * 16;
                float* dst = out + (size_t)rank * 15;
#pragma unroll
                for (int c = 0; c < 15; ++c) dst[c] = src[c];
            }
        }
    }
    // zero-fill ranks never produced
    for (int r = (int)totk + tid; r < POST_K; r += 1024) {
        float* dst = out + (size_t)r * 15;
#pragma unroll
        for (int c = 0; c < 15; ++c) dst[c] = 0.f;
    }
}

extern "C" void kernel_launch(void* const* d_in, const int* in_sizes, int n_in,
                              void* d_out, int out_size, void* d_ws, size_t ws_size,
                              hipStream_t stream) {
    const float* loc = (const float*)d_in[0];
    const float2* conf2 = (const float2*)d_in[1];
    const float* lmk = (const float*)d_in[2];
    const float* pri = (const float*)d_in[3];
    const int* imw = (const int*)d_in[4];
    const int* imh = (const int*)d_in[5];
    float* out = (float*)d_out;
    char* base = (char*)d_ws;

    // workspace layout (bytes); total 3,767,232 (< 3,808,896 proven in R3-R8)
    u32* bfill  = (u32*)(base + 32768);     //  32768  (zeroed by histscan)
    u32* bsel   = (u32*)(base + 65536);     //  64     (always written by histscan)
    u64* validm = (u64*)(base + 65600);     //  1024   (zeroed by histscan)
    u32* bstart = (u32*)(base + 67648);     //  32768
    u64* cand   = (u64*)(base + 100416);    //  65536
    float* rows = (float*)(base + 165952);  //  320000 (5000 x 16)
    float4* boxes = (float4*)(base + 485952); // 80896 (NPAD x 16; pads read-garbage-OK)
    u64* mask   = (u64*)(base + 566848);    //  3200384 (PRE_K x STR x 8)

    histscan_kernel<<<1, 1024, 0, stream>>>(conf2, bsel, bstart, bfill, validm);
    compact_kernel<<<(N_IN + 255) / 256, 256, 0, stream>>>(conf2, bsel, bstart, bfill, cand);
    rankdec_kernel<<<24, 256, 0, stream>>>(cand, bstart, bfill, bsel, (const float4*)loc,
                                           (const float4*)pri, lmk, imw, imh,
                                           (float4*)rows, boxes, validm);
    mask_kernel<<<NW * (NW + 1) / 2, 64, 0, stream>>>(boxes, mask);
    reduce_scatter_kernel<<<1, 1024, 0, stream>>>(mask, validm, rows, out);
}